// Round 1
// baseline (1641.716 us; speedup 1.0000x reference)
//
#include <hip/hip_runtime.h>

#define M_   512
#define N_   512
#define INF_ 1e5f
#define T_   32            // interior tile written back per block
#define K_   8             // Jacobi iterations per launch (halo width)
#define TW   (T_ + 2*K_)   // 48: staged tile width
#define TILE_CELLS (TW*TW) // 2304
#define UPD  (TW - 2)      // 46: updatable region width per local iter

// ---------------- init: u = INF everywhere, 0 at source ----------------
__global__ __launch_bounds__(256) void init_u(float* __restrict__ u,
                                              const int* __restrict__ m1p,
                                              const int* __restrict__ n1p) {
    int idx = blockIdx.x * 256 + threadIdx.x;
    int src = m1p[0] * N_ + n1p[0];
    if (idx < M_ * N_) u[idx] = (idx == src) ? 0.0f : INF_;
}

// ---------------- temporally-blocked Jacobi: K_ sweeps per launch ----------------
__global__ __launch_bounds__(256) void jacobi_k(const float* __restrict__ u_in,
                                                float* __restrict__ u_out,
                                                const float* __restrict__ f) {
    __shared__ float sA[TILE_CELLS];
    __shared__ float sB[TILE_CELLS];
    __shared__ float sF[TILE_CELLS];
    const int tid = threadIdx.x;
    const int bx  = blockIdx.x & 15;   // tile col (along N)
    const int by  = blockIdx.x >> 4;   // tile row (along M)
    const int gr0 = by * T_ - K_;
    const int gc0 = bx * T_ - K_;

    // stage tile + halo; off-grid cells = INF (reference pads with INF each sweep)
    for (int idx = tid; idx < TILE_CELLS; idx += 256) {
        int r = idx / TW, c = idx - r * TW;
        int gr = gr0 + r, gc = gc0 + c;
        float uv = INF_, fv = 1.0f;
        if ((unsigned)gr < (unsigned)M_ && (unsigned)gc < (unsigned)N_) {
            int g = gr * N_ + gc;
            uv = u_in[g];
            fv = f[g];            // H == 1.0 so fh == f
        }
        sA[idx] = uv;
        sB[idx] = uv;             // ring cells of both buffers stay fixed
        sF[idx] = fv;
    }
    __syncthreads();

    float* sin_  = sA;
    float* sout_ = sB;
    #pragma unroll 1
    for (int it = 0; it < K_; ++it) {
        for (int idx = tid; idx < UPD * UPD; idx += 256) {
            int r = idx / UPD;
            int c = idx - r * UPD;
            r += 1; c += 1;
            int gr = gr0 + r, gc = gc0 + c;
            // only physical-grid cells ever update; off-grid stays INF forever
            if ((unsigned)gr < (unsigned)M_ && (unsigned)gc < (unsigned)N_) {
                float uc = sin_[r * TW + c];
                float up = sin_[(r - 1) * TW + c];
                float dn = sin_[(r + 1) * TW + c];
                float lf = sin_[r * TW + c - 1];
                float rt = sin_[r * TW + c + 1];
                float a  = fminf(up, dn);           // min over x-neighbors
                float b  = fminf(lf, rt);           // min over y-neighbors
                float fh = sF[r * TW + c];
                float amb  = a - b;
                float one  = fminf(a, b) + fh;
                float disc = 2.0f * fh * fh - amb * amb;
                float two  = 0.5f * (a + b + sqrtf(fmaxf(disc, 0.0f)));
                float un   = (fabsf(amb) >= fh) ? one : two;
                sout_[r * TW + c] = fminf(uc, un);
            }
        }
        __syncthreads();
        float* t = sin_; sin_ = sout_; sout_ = t;
    }

    // write back the valid 32x32 interior (valid region after K_ iters = [K_, TW-K_)^2)
    for (int idx = tid; idx < T_ * T_; idx += 256) {
        int r = idx >> 5, c = idx & 31;
        u_out[(gr0 + K_ + r) * N_ + (gc0 + K_ + c)] = sin_[(r + K_) * TW + (c + K_)];
    }
}

// ---------------- bilinear gather (reference quirks preserved) ----------------
__device__ __forceinline__ float bil1(const float* __restrict__ u, float gx, float gy) {
    float xu = ceilf(gx),  xl = floorf(gx);
    float yu = ceilf(gy),  yl = floorf(gy);
    int guu = (int)(xu * (float)N_ + yu);
    int gul = (int)(xu * (float)N_ + yl);
    int gll = (int)(xl * (float)N_ + yl);
    float f22 = u[guu];
    float f21 = u[gul];
    float f11 = u[gll];
    float xh = xu - gx, xlw = gx - xl;
    float yh = yu - gy, ylw = gy - yl;
    float w11 = xh * yh, w12 = xh * ylw, w21 = xlw * yh, w22 = xlw * ylw;
    // note: f_x2y1 used for BOTH w12 and w21 terms, f_x1y2 unused (source quirk); DX*DY == 1
    return w11 * f11 + w12 * f21 + w21 * f21 + w22 * f22;
}

__global__ __launch_bounds__(256) void bilin(const float* __restrict__ u,
                                             const float* __restrict__ gx,
                                             const float* __restrict__ gy,
                                             float* __restrict__ out, int q4) {
    int i = blockIdx.x * blockDim.x + threadIdx.x;
    int stride = gridDim.x * blockDim.x;
    for (; i < q4; i += stride) {
        float4 x = reinterpret_cast<const float4*>(gx)[i];
        float4 y = reinterpret_cast<const float4*>(gy)[i];
        float4 o;
        o.x = bil1(u, x.x, y.x);
        o.y = bil1(u, x.y, y.y);
        o.z = bil1(u, x.z, y.z);
        o.w = bil1(u, x.w, y.w);
        reinterpret_cast<float4*>(out)[i] = o;
    }
}

extern "C" void kernel_launch(void* const* d_in, const int* in_sizes, int n_in,
                              void* d_out, int out_size, void* d_ws, size_t ws_size,
                              hipStream_t stream) {
    const float* f  = (const float*)d_in[0];
    const float* gx = (const float*)d_in[1];
    const float* gy = (const float*)d_in[2];
    const int*   m1 = (const int*)d_in[3];
    const int*   n1 = (const int*)d_in[4];
    float* out = (float*)d_out;

    float* ua = (float*)d_ws;
    float* ub = ua + M_ * N_;
    const int Q = in_sizes[1];

    init_u<<<(M_ * N_ + 255) / 256, 256, 0, stream>>>(ua, m1, n1);

    const float* src = ua;
    float*       dst = ub;
    // 75 launches x 8 sweeps = 600 Jacobi iterations, exactly as the reference
    for (int l = 0; l < 75; ++l) {
        jacobi_k<<<256, 256, 0, stream>>>(src, dst, f);
        float* t = (float*)src; src = dst; dst = t;
    }

    bilin<<<2048, 256, 0, stream>>>(src, gx, gy, out, Q / 4);
}

// Round 4
// 1081.718 us; speedup vs baseline: 1.5177x; 1.5177x over previous
//
#include <hip/hip_runtime.h>

#define M_    512
#define N_    512
#define INF_  1e5f
#define FBIG  1e30f          // "slowness" for off-grid cells: forces update >= 1e30 -> frozen at INF
#define T_    32             // interior tile written back per block
#define K_    24             // Jacobi iterations per launch (halo width); 25 launches x 24 = 600
#define TW    80             // T_ + 2*K_ staged tile width
#define STRIDE 84            // LDS row stride (pad: staged col j -> lds col j+1; 84*4B = 16B-aligned rows)
#define NROWS 80
#define SPR   39             // strips of 2 per row: interior cols lds 2..79
#define NSTRIPS (SPR * 78)   // interior rows lds 1..78 -> 3042 strips
#define NTHREADS 1024

// ---------------- init: u = INF everywhere, 0 at source ----------------
__global__ __launch_bounds__(256) void init_u(float* __restrict__ u,
                                              const int* __restrict__ m1p,
                                              const int* __restrict__ n1p) {
    int idx = blockIdx.x * 256 + threadIdx.x;
    int src = m1p[0] * N_ + n1p[0];
    if (idx < M_ * N_) u[idx] = (idx == src) ? 0.0f : INF_;
}

// ---------------- temporally-blocked Jacobi: K_ sweeps per launch ----------------
__global__ __launch_bounds__(NTHREADS) void jacobi_k(const float* __restrict__ u_in,
                                                     float* __restrict__ u_out,
                                                     const float* __restrict__ f) {
    __shared__ float sA[NROWS * STRIDE];
    __shared__ float sB[NROWS * STRIDE];
    const int tid = threadIdx.x;
    const int bx  = blockIdx.x & 15;
    const int by  = blockIdx.x >> 4;
    const int gr0 = by * T_ - K_;
    const int gc0 = bx * T_ - K_;

    // stage u tile+halo into BOTH buffers (ring cells of both stay fixed forever)
    for (int idx = tid; idx < NROWS * TW; idx += NTHREADS) {
        int r = idx / TW, j = idx - r * TW;
        int gr = gr0 + r, gc = gc0 + j;
        float uv = INF_;
        if ((unsigned)gr < (unsigned)M_ && (unsigned)gc < (unsigned)N_)
            uv = u_in[gr * N_ + gc];
        int p = r * STRIDE + j + 1;
        sA[p] = uv;
        sB[p] = uv;
    }

    // fixed per-thread strips: addresses + f in registers, no div/bounds in hot loop
    int soff[3]; float f0v[3], f1v[3], t0v[3], t1v[3];
    #pragma unroll
    for (int i = 0; i < 3; ++i) {
        int sidx = tid + i * NTHREADS;
        soff[i] = -1;
        if (sidx < NSTRIPS) {
            int sr = sidx / SPR;
            int sc = sidx - sr * SPR;
            int r = sr + 1;            // lds row 1..78
            int c = sc * 2 + 2;        // lds col 2,4,...,78 (8B-aligned for b64)
            soff[i] = r * STRIDE + c;
            int gr  = gr0 + r;
            int gca = gc0 + c - 1;     // staged col = lds col - 1
            int gcb = gc0 + c;
            float fa = FBIG, fb = FBIG;
            if ((unsigned)gr < (unsigned)M_) {
                if ((unsigned)gca < (unsigned)N_) fa = f[gr * N_ + gca];
                if ((unsigned)gcb < (unsigned)N_) fb = f[gr * N_ + gcb];
            }
            f0v[i] = fa; f1v[i] = fb;
            t0v[i] = 2.0f * fa * fa;   // 2*fh^2 (H==1); inf for off-grid -> update stays huge
            t1v[i] = 2.0f * fb * fb;
        }
    }
    __syncthreads();

    float* cur = sA;
    float* nxt = sB;
    for (int it = 0; it < K_; ++it) {
        #pragma unroll
        for (int i = 0; i < 3; ++i) {
            if (soff[i] >= 0) {
                const int off = soff[i];
                float2 up = *(const float2*)(cur + off - STRIDE);
                float2 dn = *(const float2*)(cur + off + STRIDE);
                float2 ct = *(const float2*)(cur + off);
                float lf = cur[off - 1];
                float rt = cur[off + 2];
                // cell 0: x-neighbors up.x/dn.x, y-neighbors lf/ct.y
                float a0 = fminf(up.x, dn.x), b0 = fminf(lf, ct.y);
                float amb0 = a0 - b0;
                float one0 = fminf(a0, b0) + f0v[i];
                float dis0 = fmaf(-amb0, amb0, t0v[i]);
                float two0 = 0.5f * (a0 + b0 + sqrtf(fmaxf(dis0, 0.0f)));
                float un0  = (fabsf(amb0) >= f0v[i]) ? one0 : two0;
                un0 = fminf(ct.x, un0);
                // cell 1: x-neighbors up.y/dn.y, y-neighbors ct.x/rt (old value, Jacobi)
                float a1 = fminf(up.y, dn.y), b1 = fminf(ct.x, rt);
                float amb1 = a1 - b1;
                float one1 = fminf(a1, b1) + f1v[i];
                float dis1 = fmaf(-amb1, amb1, t1v[i]);
                float two1 = 0.5f * (a1 + b1 + sqrtf(fmaxf(dis1, 0.0f)));
                float un1  = (fabsf(amb1) >= f1v[i]) ? one1 : two1;
                un1 = fminf(ct.y, un1);
                *(float2*)(nxt + off) = make_float2(un0, un1);
            }
        }
        __syncthreads();
        float* t = cur; cur = nxt; nxt = t;
    }

    // write back the valid 32x32 interior: staged rows/cols 24..55 -> lds [24+r][25+c]
    {
        int r = tid >> 5, c = tid & 31;
        u_out[(by * T_ + r) * N_ + bx * T_ + c] = cur[(K_ + r) * STRIDE + (K_ + 1 + c)];
    }
}

// ---------------- bilinear gather (reference quirks preserved) ----------------
__device__ __forceinline__ float bil1(const float* __restrict__ u, float gx, float gy) {
    float xu = ceilf(gx),  xl = floorf(gx);
    float yu = ceilf(gy),  yl = floorf(gy);
    int guu = (int)(xu * (float)N_ + yu);
    int gul = (int)(xu * (float)N_ + yl);
    int gll = (int)(xl * (float)N_ + yl);
    float f22 = u[guu];
    float f21 = u[gul];
    float f11 = u[gll];
    float xh = xu - gx, xlw = gx - xl;
    float yh = yu - gy, ylw = gy - yl;
    float w11 = xh * yh, w12 = xh * ylw, w21 = xlw * yh, w22 = xlw * ylw;
    // f_x2y1 used for BOTH w12 and w21 terms, f_x1y2 unused (source quirk); DX*DY == 1
    return w11 * f11 + w12 * f21 + w21 * f21 + w22 * f22;
}

__global__ __launch_bounds__(256) void bilin(const float* __restrict__ u,
                                             const float* __restrict__ gx,
                                             const float* __restrict__ gy,
                                             float* __restrict__ out, int q4) {
    int i = blockIdx.x * blockDim.x + threadIdx.x;
    int stride = gridDim.x * blockDim.x;
    for (; i < q4; i += stride) {
        float4 x = reinterpret_cast<const float4*>(gx)[i];
        float4 y = reinterpret_cast<const float4*>(gy)[i];
        float4 o;
        o.x = bil1(u, x.x, y.x);
        o.y = bil1(u, x.y, y.y);
        o.z = bil1(u, x.z, y.z);
        o.w = bil1(u, x.w, y.w);
        reinterpret_cast<float4*>(out)[i] = o;
    }
}

extern "C" void kernel_launch(void* const* d_in, const int* in_sizes, int n_in,
                              void* d_out, int out_size, void* d_ws, size_t ws_size,
                              hipStream_t stream) {
    const float* f  = (const float*)d_in[0];
    const float* gx = (const float*)d_in[1];
    const float* gy = (const float*)d_in[2];
    const int*   m1 = (const int*)d_in[3];
    const int*   n1 = (const int*)d_in[4];
    float* out = (float*)d_out;

    float* ua = (float*)d_ws;
    float* ub = ua + M_ * N_;
    const int Q = in_sizes[1];

    init_u<<<(M_ * N_ + 255) / 256, 256, 0, stream>>>(ua, m1, n1);

    const float* src = ua;
    float*       dst = ub;
    // 25 launches x 24 sweeps = 600 Jacobi iterations, exactly as the reference
    for (int l = 0; l < 25; ++l) {
        jacobi_k<<<256, NTHREADS, 0, stream>>>(src, dst, f);
        float* t = (float*)src; src = dst; dst = t;
    }

    bilin<<<4096, 256, 0, stream>>>(src, gx, gy, out, Q / 4);
}

// Round 7
// 781.542 us; speedup vs baseline: 2.1006x; 1.3841x over previous
//
#include <hip/hip_runtime.h>

#define M_    512
#define N_    512
#define INF_  1e5f
#define FBIG  1e30f        // off-grid "slowness": updates become >=1e30, fmin keeps INF -> exact INF pad semantics
#define T_    32           // interior tile written back per block
#define K_    24           // Jacobi iters per launch (halo); 25 launches x 24 = 600
#define TW    80           // staged tile width (T_+2K_)
#define SD    88           // LDS row stride in dwords (16B-aligned rows: 88*4=352=16*22)
#define QPR   20           // 4-cell quads per row (staged cols 1..80, tail cols garbage-don't-care)
#define NQ    (78*QPR)     // 1560 quads (staged rows 1..78)
#define NT    1024

#if !__has_builtin(__builtin_amdgcn_sqrtf)
#define __builtin_amdgcn_sqrtf sqrtf
#endif

// ---------------- init: u = INF everywhere, 0 at source ----------------
__global__ __launch_bounds__(256) void init_u(float* __restrict__ u,
                                              const int* __restrict__ m1p,
                                              const int* __restrict__ n1p) {
    int idx = blockIdx.x * 256 + threadIdx.x;
    int src = m1p[0] * N_ + n1p[0];
    if (idx < M_ * N_) u[idx] = (idx == src) ? 0.0f : INF_;
}

// Godunov upwind cell update (H==1): fast sqrt (<=1ulp), branchless select
__device__ __forceinline__ float cell_upd(float xn0, float xn1, float yn0, float yn1,
                                          float uc, float fh, float t2) {
    float a   = fminf(xn0, xn1);
    float b   = fminf(yn0, yn1);
    float amb = a - b;
    float one = fminf(a, b) + fh;
    float dis = fmaf(-amb, amb, t2);                       // 2*fh^2 - (a-b)^2
    float two = 0.5f * (a + b + __builtin_amdgcn_sqrtf(fmaxf(dis, 0.0f)));
    float un  = (fabsf(amb) >= fh) ? one : two;
    return fminf(uc, un);
}

__device__ __forceinline__ void quad_update(const float* __restrict__ cur,
                                            float* __restrict__ nxt, int off4,
                                            const float* __restrict__ fq,
                                            const float* __restrict__ tq) {
    const int off = off4 * 4;                              // 16B-aligned dword offset
    float4 up = *(const float4*)(cur + off - SD);
    float4 dn = *(const float4*)(cur + off + SD);
    float4 ct = *(const float4*)(cur + off);
    float  lf = cur[off - 1];
    float  rt = cur[off + 4];
    float4 o;
    o.x = cell_upd(up.x, dn.x, lf,   ct.y, ct.x, fq[0], tq[0]);
    o.y = cell_upd(up.y, dn.y, ct.x, ct.z, ct.y, fq[1], tq[1]);
    o.z = cell_upd(up.z, dn.z, ct.y, ct.w, ct.z, fq[2], tq[2]);
    o.w = cell_upd(up.w, dn.w, ct.z, rt,   ct.w, fq[3], tq[3]);
    *(float4*)(nxt + off) = o;
}

// ---------------- temporally-blocked Jacobi with trapezoidal shrink ----------------
// State t is correct on staged [t, 80-t)^2; iter t computes staged [t+1, 79-t)^2.
// Cells outside the shrinking region may receive garbage - provably never read
// by any later needed cell. Off-grid cells stay exactly INF (FBIG forces update>=1e30).
__global__ __launch_bounds__(NT) void jacobi_k(const float* __restrict__ u_in,
                                               float* __restrict__ u_out,
                                               const float* __restrict__ f) {
    __shared__ float sA[TW * SD];
    __shared__ float sB[TW * SD];                          // no staging needed: fully written at iter 0
    const int tid = threadIdx.x;
    const int bx  = blockIdx.x & 15;
    const int by  = blockIdx.x >> 4;
    const int gr0 = by * T_ - K_;
    const int gc0 = bx * T_ - K_;

    // stage u tile+halo into sA (lds col = staged col + 3)
    for (int idx = tid; idx < TW * TW; idx += NT) {
        int r = idx / TW, c = idx - r * TW;
        int gr = gr0 + r, gc = gc0 + c;
        float uv = INF_;
        if ((unsigned)gr < (unsigned)M_ && (unsigned)gc < (unsigned)N_)
            uv = u_in[gr * N_ + gc];
        sA[r * SD + c + 3] = uv;
    }

    // fixed per-thread quads: thread tid owns quad tid (always) and quad tid+1024 (if <1560)
    int r0, c0, off0, r1 = 0, c1 = 0, off1 = -1;
    float fq0[4], tq0[4], fq1[4], tq1[4];
    {
        int qr = tid / QPR, qk = tid - qr * QPR;
        r0 = qr + 1; c0 = 1 + 4 * qk;                      // staged row 1..52ish, staged col 1,5,..,77
        off0 = 22 * r0 + 1 + qk;                           // dword offset / 4
        #pragma unroll
        for (int j = 0; j < 4; ++j) {
            int gr = gr0 + r0, gc = gc0 + c0 + j;
            float fv = FBIG;
            if ((unsigned)gr < (unsigned)M_ && (unsigned)gc < (unsigned)N_)
                fv = f[gr * N_ + gc];
            fq0[j] = fv; tq0[j] = 2.0f * fv * fv;
        }
    }
    if (tid + NT < NQ) {
        int qi = tid + NT;
        int qr = qi / QPR, qk = qi - qr * QPR;
        r1 = qr + 1; c1 = 1 + 4 * qk;
        off1 = 22 * r1 + 1 + qk;
        #pragma unroll
        for (int j = 0; j < 4; ++j) {
            int gr = gr0 + r1, gc = gc0 + c1 + j;
            float fv = FBIG;
            if ((unsigned)gr < (unsigned)M_ && (unsigned)gc < (unsigned)N_)
                fv = f[gr * N_ + gc];
            fq1[j] = fv; tq1[j] = 2.0f * fv * fv;
        }
    }
    __syncthreads();

    float* cur = sA;
    float* nxt = sB;
    for (int t = 0; t < K_; ++t) {
        const int lo = t + 1, hi = 78 - t;                 // active staged range [lo, hi]
        if (r0 >= lo && r0 <= hi && c0 + 3 >= lo && c0 <= hi)
            quad_update(cur, nxt, off0, fq0, tq0);
        if (off1 >= 0 && r1 >= lo && r1 <= hi && c1 + 3 >= lo && c1 <= hi)
            quad_update(cur, nxt, off1, fq1, tq1);
        __syncthreads();
        float* tmp = cur; cur = nxt; nxt = tmp;
    }

    // write back valid 32x32 interior: staged [24,56)^2 -> lds rows 24..55, cols 27..58
    {
        int r = tid >> 5, c = tid & 31;
        u_out[(by * T_ + r) * N_ + bx * T_ + c] = cur[(K_ + r) * SD + (K_ + 3 + c)];
    }
}

// ---------------- 2x2 quad table: one 16B gather per query point ----------------
__global__ __launch_bounds__(256) void build_quad(const float* __restrict__ u,
                                                  float4* __restrict__ uq) {
    int idx = blockIdx.x * 256 + threadIdx.x;              // 512*512
    int i = idx >> 9, j = idx & 511;
    int i1 = (i < M_ - 1) ? i + 1 : i;
    int j1 = (j < N_ - 1) ? j + 1 : j;
    float a = u[(i  << 9) | j];
    float b = u[(i  << 9) | j1];
    float c = u[(i1 << 9) | j];
    float d = u[(i1 << 9) | j1];
    uq[idx] = make_float4(a, b, c, d);
}

__device__ __forceinline__ float bil1(const float4* __restrict__ uq, float gx, float gy) {
    float xu = ceilf(gx),  xl = floorf(gx);
    float yu = ceilf(gy),  yl = floorf(gy);
    int   ixl = (int)xl,   iyl = (int)yl;
    float4 q = uq[(ixl << 9) + iyl];                       // (u[xl][yl], u[xl][yl+1], u[xl+1][yl], u[xl+1][yl+1])
    bool  xi = (xu == xl), yi = (yu == yl);
    float f11 = q.x;
    float f21 = xi ? q.x : q.z;                            // u[xu][yl]
    float f22 = xi ? (yi ? q.x : q.y) : (yi ? q.z : q.w);  // u[xu][yu]
    float xh = xu - gx, xlw = gx - xl;
    float yh = yu - gy, ylw = gy - yl;
    float w11 = xh * yh, w12 = xh * ylw, w21 = xlw * yh, w22 = xlw * ylw;
    // f_x2y1 used for BOTH w12 and w21 terms, f_x1y2 unused (source quirk); DX*DY == 1
    return w11 * f11 + w12 * f21 + w21 * f21 + w22 * f22;
}

__global__ __launch_bounds__(256) void bilin(const float4* __restrict__ uq,
                                             const float* __restrict__ gx,
                                             const float* __restrict__ gy,
                                             float* __restrict__ out, int q4) {
    int i = blockIdx.x * blockDim.x + threadIdx.x;
    int stride = gridDim.x * blockDim.x;
    for (; i < q4; i += stride) {
        float4 x = reinterpret_cast<const float4*>(gx)[i];
        float4 y = reinterpret_cast<const float4*>(gy)[i];
        float4 o;
        o.x = bil1(uq, x.x, y.x);
        o.y = bil1(uq, x.y, y.y);
        o.z = bil1(uq, x.z, y.z);
        o.w = bil1(uq, x.w, y.w);
        reinterpret_cast<float4*>(out)[i] = o;
    }
}

extern "C" void kernel_launch(void* const* d_in, const int* in_sizes, int n_in,
                              void* d_out, int out_size, void* d_ws, size_t ws_size,
                              hipStream_t stream) {
    const float* f  = (const float*)d_in[0];
    const float* gx = (const float*)d_in[1];
    const float* gy = (const float*)d_in[2];
    const int*   m1 = (const int*)d_in[3];
    const int*   n1 = (const int*)d_in[4];
    float* out = (float*)d_out;

    float*  ua = (float*)d_ws;
    float*  ub = ua + M_ * N_;
    float4* uq = (float4*)(ub + M_ * N_);                  // 4 MB quad table (16B-aligned)
    const int Q = in_sizes[1];

    init_u<<<(M_ * N_ + 255) / 256, 256, 0, stream>>>(ua, m1, n1);

    const float* src = ua;
    float*       dst = ub;
    // 25 launches x 24 sweeps = 600 Jacobi iterations, exactly as the reference
    for (int l = 0; l < 25; ++l) {
        jacobi_k<<<256, NT, 0, stream>>>(src, dst, f);
        float* t = (float*)src; src = dst; dst = t;
    }

    build_quad<<<(M_ * N_) / 256, 256, 0, stream>>>(src, uq);
    bilin<<<4096, 256, 0, stream>>>(uq, gx, gy, out, Q / 4);
}

// Round 8
// 724.648 us; speedup vs baseline: 2.2655x; 1.0785x over previous
//
#include <hip/hip_runtime.h>

#define M_    512
#define N_    512
#define INF_  1e5f
#define FBIG  1e30f        // off-grid "slowness": updates become >=1e30, fmin keeps INF -> exact INF pad semantics
#define T_    32           // interior tile written back per block
#define K_    24           // Jacobi iters per launch (halo); 25 launches x 24 = 600
#define TW    80           // staged tile width (T_+2K_)
#define SD    88           // LDS row stride in dwords (16B-aligned rows: 88*4=352=16*22)
#define QPR   20           // 4-cell quads per row (staged cols 1..80, tail cols slop-don't-care)
#define NQ    (78*QPR)     // 1560 quads (staged rows 1..78)
#define NT    1024

#if !__has_builtin(__builtin_amdgcn_sqrtf)
#define __builtin_amdgcn_sqrtf sqrtf
#endif

// ---------------- init: u = INF everywhere, 0 at source ----------------
__global__ __launch_bounds__(256) void init_u(float* __restrict__ u,
                                              const int* __restrict__ m1p,
                                              const int* __restrict__ n1p) {
    int idx = blockIdx.x * 256 + threadIdx.x;
    int src = m1p[0] * N_ + n1p[0];
    if (idx < M_ * N_) u[idx] = (idx == src) ? 0.0f : INF_;
}

// Godunov upwind cell update (H==1): fast sqrt (<=1ulp), branchless select
__device__ __forceinline__ float cell_upd(float xn0, float xn1, float yn0, float yn1,
                                          float uc, float fh, float t2) {
    float a   = fminf(xn0, xn1);
    float b   = fminf(yn0, yn1);
    float amb = a - b;
    float one = fminf(a, b) + fh;
    float dis = fmaf(-amb, amb, t2);                       // 2*fh^2 - (a-b)^2
    float two = 0.5f * (a + b + __builtin_amdgcn_sqrtf(fmaxf(dis, 0.0f)));
    float un  = (fabsf(amb) >= fh) ? one : two;
    return fminf(uc, un);
}

__device__ __forceinline__ void quad_update(const float* __restrict__ cur,
                                            float* __restrict__ nxt, int off4,
                                            const float* __restrict__ fq,
                                            const float* __restrict__ tq) {
    const int off = off4 * 4;                              // 16B-aligned dword offset
    float4 up = *(const float4*)(cur + off - SD);
    float4 dn = *(const float4*)(cur + off + SD);
    float4 ct = *(const float4*)(cur + off);
    float  lf = cur[off - 1];
    float  rt = cur[off + 4];
    float4 o;
    o.x = cell_upd(up.x, dn.x, lf,   ct.y, ct.x, fq[0], tq[0]);
    o.y = cell_upd(up.y, dn.y, ct.x, ct.z, ct.y, fq[1], tq[1]);
    o.z = cell_upd(up.z, dn.z, ct.y, ct.w, ct.z, fq[2], tq[2]);
    o.w = cell_upd(up.w, dn.w, ct.z, rt,   ct.w, fq[3], tq[3]);
    *(float4*)(nxt + off) = o;
}

// ---------------- temporally-blocked Jacobi with trapezoidal shrink ----------------
// State t is correct on staged [t, 80-t)^2; iter t computes staged [t+1, 79-t)^2.
// Quad active at iter t  <=>  it intersects [t+1, 78-t]  <=>  t < life where
// life = min(r0, 79-r0, c0+3, 79-c0). Slop cells (outside the shrinking region)
// may receive garbage - provably never read by any later needed cell.
__global__ __launch_bounds__(NT) void jacobi_k(const float* __restrict__ u_in,
                                               float* __restrict__ u_out,
                                               const float* __restrict__ f) {
    __shared__ float sA[TW * SD];
    __shared__ float sB[TW * SD];
    const int tid = threadIdx.x;
    const int bx  = blockIdx.x & 15;
    const int by  = blockIdx.x >> 4;
    const int gr0 = by * T_ - K_;
    const int gc0 = bx * T_ - K_;

    // stage u tile+halo into sA (lds col = staged col + 3)
    for (int idx = tid; idx < TW * TW; idx += NT) {
        int r = idx / TW, c = idx - r * TW;
        int gr = gr0 + r, gc = gc0 + c;
        float uv = INF_;
        if ((unsigned)gr < (unsigned)M_ && (unsigned)gc < (unsigned)N_)
            uv = u_in[gr * N_ + gc];
        sA[r * SD + c + 3] = uv;
    }

    // fixed per-thread quads: thread tid owns quad tid (always) and quad tid+1024 (if <NQ)
    int off0, off1 = 0, life0, life1 = 0;
    float fq0[4], tq0[4], fq1[4], tq1[4];
    {
        int qr = tid / QPR, qk = tid - qr * QPR;
        int r0 = qr + 1, c0 = 1 + 4 * qk;
        off0  = 22 * r0 + 1 + qk;                          // offset in float4 units
        life0 = min(min(r0, 79 - r0), min(c0 + 3, 79 - c0));
        #pragma unroll
        for (int j = 0; j < 4; ++j) {
            int gr = gr0 + r0, gc = gc0 + c0 + j;
            float fv = FBIG;
            if ((unsigned)gr < (unsigned)M_ && (unsigned)gc < (unsigned)N_)
                fv = f[gr * N_ + gc];
            fq0[j] = fv; tq0[j] = 2.0f * fv * fv;
        }
    }
    if (tid + NT < NQ) {
        int qi = tid + NT;
        int qr = qi / QPR, qk = qi - qr * QPR;
        int r1 = qr + 1, c1 = 1 + 4 * qk;
        off1  = 22 * r1 + 1 + qk;
        life1 = min(min(r1, 79 - r1), min(c1 + 3, 79 - c1));
        #pragma unroll
        for (int j = 0; j < 4; ++j) {
            int gr = gr0 + r1, gc = gc0 + c1 + j;
            float fv = FBIG;
            if ((unsigned)gr < (unsigned)M_ && (unsigned)gc < (unsigned)N_)
                fv = f[gr * N_ + gc];
            fq1[j] = fv; tq1[j] = 2.0f * fv * fv;
        }
    }
    __syncthreads();

    float* cur = sA;
    float* nxt = sB;
    for (int t = 0; t < K_; ++t) {
        if (t < life0) quad_update(cur, nxt, off0, fq0, tq0);
        if (t < life1) quad_update(cur, nxt, off1, fq1, tq1);
        __syncthreads();
        float* tmp = cur; cur = nxt; nxt = tmp;
    }

    // write back valid 32x32 interior: staged [24,56)^2 -> lds rows 24..55, cols 27..58
    {
        int r = tid >> 5, c = tid & 31;
        u_out[(by * T_ + r) * N_ + bx * T_ + c] = cur[(K_ + r) * SD + (K_ + 3 + c)];
    }
}

// ---------------- bilinear gather: 3 dword gathers into L2-resident 1MB u ----------------
__device__ __forceinline__ float bil1(const float* __restrict__ u, float gx, float gy) {
    float xu = ceilf(gx),  xl = floorf(gx);
    float yu = ceilf(gy),  yl = floorf(gy);
    int guu = (int)(xu * (float)N_ + yu);
    int gul = (int)(xu * (float)N_ + yl);
    int gll = (int)(xl * (float)N_ + yl);
    float f22 = u[guu];
    float f21 = u[gul];
    float f11 = u[gll];
    float xh = xu - gx, xlw = gx - xl;
    float yh = yu - gy, ylw = gy - yl;
    float w11 = xh * yh, w12 = xh * ylw, w21 = xlw * yh, w22 = xlw * ylw;
    // f_x2y1 used for BOTH w12 and w21 terms, f_x1y2 unused (source quirk); DX*DY == 1
    return w11 * f11 + w12 * f21 + w21 * f21 + w22 * f22;
}

__global__ __launch_bounds__(256) void bilin(const float* __restrict__ u,
                                             const float* __restrict__ gx,
                                             const float* __restrict__ gy,
                                             float* __restrict__ out, int q4) {
    int i = blockIdx.x * blockDim.x + threadIdx.x;
    int stride = gridDim.x * blockDim.x;
    for (; i < q4; i += stride) {
        float4 x = reinterpret_cast<const float4*>(gx)[i];
        float4 y = reinterpret_cast<const float4*>(gy)[i];
        float4 o;
        o.x = bil1(u, x.x, y.x);
        o.y = bil1(u, x.y, y.y);
        o.z = bil1(u, x.z, y.z);
        o.w = bil1(u, x.w, y.w);
        reinterpret_cast<float4*>(out)[i] = o;
    }
}

extern "C" void kernel_launch(void* const* d_in, const int* in_sizes, int n_in,
                              void* d_out, int out_size, void* d_ws, size_t ws_size,
                              hipStream_t stream) {
    const float* f  = (const float*)d_in[0];
    const float* gx = (const float*)d_in[1];
    const float* gy = (const float*)d_in[2];
    const int*   m1 = (const int*)d_in[3];
    const int*   n1 = (const int*)d_in[4];
    float* out = (float*)d_out;

    float* ua = (float*)d_ws;
    float* ub = ua + M_ * N_;
    const int Q = in_sizes[1];

    init_u<<<(M_ * N_ + 255) / 256, 256, 0, stream>>>(ua, m1, n1);

    const float* src = ua;
    float*       dst = ub;
    // 25 launches x 24 sweeps = 600 Jacobi iterations, exactly as the reference
    for (int l = 0; l < 25; ++l) {
        jacobi_k<<<256, NT, 0, stream>>>(src, dst, f);
        float* t = (float*)src; src = dst; dst = t;
    }

    bilin<<<4096, 256, 0, stream>>>(src, gx, gy, out, Q / 4);
}